// Round 1
// baseline (1385.485 us; speedup 1.0000x reference)
//
#include <hip/hip_runtime.h>
#include <hip/hip_bf16.h>

#define N_ATOMS   500000
#define N_BONDS   1000000
#define MAX_NB    6
#define ATOM_FDIM 133
#define BOND_FDIM 14
#define HIDDEN    128
#define N_MOLS    25000
#define APM       20

typedef __attribute__((ext_vector_type(8))) short short8;
typedef __attribute__((ext_vector_type(4))) float f32x4;
typedef unsigned short u16;
typedef unsigned int   u32;

__device__ __forceinline__ float bf2f(u16 u) {
    u32 t = ((u32)u) << 16;
    return __builtin_bit_cast(float, t);
}
__device__ __forceinline__ u16 f2bf(float f) {
    u32 t = __builtin_bit_cast(u32, f);
    t += 0x7FFFu + ((t >> 16) & 1u);
    return (u16)(t >> 16);
}

// ---------------- weight prep: fp32 -> padded bf16 ----------------
// Wi: [128][133] -> [128][160]; Wh: [128][142] -> [128][160]
// Wo: [128][261] -> [128][288]  (k<133 atoms part; 133..159 zero; 160..287 = msg part)
__global__ void prep_weights(const float* __restrict__ Wi, const float* __restrict__ Wh,
                             const float* __restrict__ Wo,
                             u16* __restrict__ Wip, u16* __restrict__ Whp, u16* __restrict__ Wop) {
    int stride = gridDim.x * blockDim.x;
    int tid = blockIdx.x * blockDim.x + threadIdx.x;
    for (int i = tid; i < 128 * 160; i += stride) {
        int r = i / 160, c = i % 160;
        Wip[i] = (c < 133) ? f2bf(Wi[r * 133 + c]) : (u16)0;
        Whp[i] = (c < 142) ? f2bf(Wh[r * 142 + c]) : (u16)0;
    }
    for (int i = tid; i < 128 * 288; i += stride) {
        int r = i / 288, c = i % 288;
        float v = 0.f;
        if (c < 133)      v = Wo[r * 261 + c];
        else if (c >= 160) v = Wo[r * 261 + (c - 27)];
        Wop[i] = f2bf(v);
    }
}

// ---------------- f_atoms fp32 [N][133] -> bf16 [N][160] ----------------
__global__ __launch_bounds__(256) void fa_convert(const float* __restrict__ fa, u16* __restrict__ out) {
    long t = (long)blockIdx.x * 256 + threadIdx.x;
    if (t >= (long)N_ATOMS * 20) return;
    int row = (int)(t / 20);
    int c8  = (int)(t % 20) * 8;
    const float* src = fa + (long)row * ATOM_FDIM;
    u16 u[8];
#pragma unroll
    for (int e = 0; e < 8; e++) {
        int c = c8 + e;
        u[e] = (c < ATOM_FDIM) ? f2bf(src[c]) : (u16)0;
    }
    uint4 v;
    v.x = (u32)u[0] | ((u32)u[1] << 16);
    v.y = (u32)u[2] | ((u32)u[3] << 16);
    v.z = (u32)u[4] | ((u32)u[5] << 16);
    v.w = (u32)u[6] | ((u32)u[7] << 16);
    *(uint4*)(out + (long)row * 160 + c8) = v;
}

// ---------------- bond pre-sum: sum_j f_bonds[a2b[:,j]] -> bf16 [N][32] ----------------
__global__ __launch_bounds__(256) void bond_gather(const float* __restrict__ fb, const int* __restrict__ a2b,
                                                   u16* __restrict__ outp) {
    long t = (long)blockIdx.x * 256 + threadIdx.x;
    int atom = (int)(t >> 4);
    int c2   = (int)(t & 15);
    if (atom >= N_ATOMS) return;
    int c0 = 2 * c2, c1 = c0 + 1;
    float s0 = 0.f, s1 = 0.f;
    if (c0 < BOND_FDIM) {
#pragma unroll
        for (int j = 0; j < MAX_NB; j++) {
            int idx = a2b[atom * 6 + j];
            const float* row = fb + (long)idx * BOND_FDIM;
            s0 += row[c0];
            if (c1 < BOND_FDIM) s1 += row[c1];
        }
    }
    *(u32*)(outp + (long)atom * 32 + c0) = (u32)f2bf(s0) | ((u32)f2bf(s1) << 16);
}

// ---------------- gather-relu-sum: dst[a] = sum_j relu(src[a2a[a,j]]) (bf16 128-wide) ---
__global__ __launch_bounds__(256) void gather_relu_sum(const u16* __restrict__ src,
                                                       const int* __restrict__ a2a,
                                                       u16* __restrict__ dst) {
    long t = (long)blockIdx.x * 256 + threadIdx.x;
    int atom = (int)(t >> 4);
    int c8   = (int)(t & 15) << 3;
    float s[8] = {0, 0, 0, 0, 0, 0, 0, 0};
#pragma unroll
    for (int j = 0; j < MAX_NB; j++) {
        int idx = a2a[atom * 6 + j];
        uint4 v = *(const uint4*)(src + (long)idx * 128 + c8);
        u32 w[4] = {v.x, v.y, v.z, v.w};
#pragma unroll
        for (int q = 0; q < 4; q++) {
            s[2 * q]     += fmaxf(bf2f((u16)(w[q] & 0xFFFFu)), 0.f);
            s[2 * q + 1] += fmaxf(bf2f((u16)(w[q] >> 16)), 0.f);
        }
    }
    uint4 o;
    o.x = (u32)f2bf(s[0]) | ((u32)f2bf(s[1]) << 16);
    o.y = (u32)f2bf(s[2]) | ((u32)f2bf(s[3]) << 16);
    o.z = (u32)f2bf(s[4]) | ((u32)f2bf(s[5]) << 16);
    o.w = (u32)f2bf(s[6]) | ((u32)f2bf(s[7]) << 16);
    *(uint4*)(dst + (long)atom * 128 + c8) = o;
}

// ---------------- GEMM: Out[N][128] = concat(A0,A1)[N][32*KB] @ Wp^T + bias (+Xadd) ----
// Wp is bf16 [128][32*KB] row-major (B[k][n] = Wp[n][k]); all stored pre-activation.
template <int KB0, int KB1, bool ADDX>
__global__ __launch_bounds__(256) void gemm_mp(const u16* __restrict__ A0, int ldA0,
                                               const u16* __restrict__ A1, int ldA1,
                                               const u16* __restrict__ Wp,
                                               const float* __restrict__ bias,
                                               const u16* __restrict__ Xadd,
                                               u16* __restrict__ Out) {
    constexpr int KB  = KB0 + KB1;
    constexpr int KP  = KB * 32;
    constexpr int LDW = KP + 8;  // +8 bf16 pad: 2-way LDS bank alias only
    __shared__ u16 ldsw[128 * LDW];
    for (int i = threadIdx.x; i < 128 * (KP / 8); i += 256) {
        int r  = i / (KP / 8);
        int c8 = (i % (KP / 8)) * 8;
        *(uint4*)(&ldsw[r * LDW + c8]) = *(const uint4*)(Wp + r * KP + c8);
    }
    __syncthreads();

    const int lane = threadIdx.x & 63;
    const int wave = threadIdx.x >> 6;
    const int lrow = lane & 15;   // A row within 16-tile / B col
    const int kg   = lane >> 4;   // k-group 0..3
    const long rowbase = (long)blockIdx.x * 128 + wave * 32;

    f32x4 acc[2][8];
#pragma unroll
    for (int m = 0; m < 2; m++)
#pragma unroll
        for (int n = 0; n < 8; n++) acc[m][n] = (f32x4){0.f, 0.f, 0.f, 0.f};

    long ar[2];
#pragma unroll
    for (int m = 0; m < 2; m++) {
        long r = rowbase + m * 16 + lrow;
        if (r >= N_ATOMS) r = N_ATOMS - 1;  // clamp (stores are guarded)
        ar[m] = r;
    }

#pragma unroll
    for (int kb = 0; kb < KB; kb++) {
        const u16* As;
        int ld, koff;
        if (kb < KB0) { As = A0; ld = ldA0; koff = kb * 32; }
        else          { As = A1; ld = ldA1; koff = (kb - KB0) * 32; }
        short8 af[2];
#pragma unroll
        for (int m = 0; m < 2; m++)
            af[m] = __builtin_bit_cast(short8, *(const uint4*)(As + ar[m] * ld + koff + kg * 8));
#pragma unroll
        for (int n = 0; n < 8; n++) {
            short8 bf = __builtin_bit_cast(short8, *(const uint4*)(&ldsw[(n * 16 + lrow) * LDW + kb * 32 + kg * 8]));
            acc[0][n] = __builtin_amdgcn_mfma_f32_16x16x32_bf16(af[0], bf, acc[0][n], 0, 0, 0);
            acc[1][n] = __builtin_amdgcn_mfma_f32_16x16x32_bf16(af[1], bf, acc[1][n], 0, 0, 0);
        }
    }

#pragma unroll
    for (int n = 0; n < 8; n++) {
        int col = n * 16 + lrow;
        float b = bias[col];
#pragma unroll
        for (int m = 0; m < 2; m++) {
            long r0 = rowbase + m * 16 + kg * 4;
#pragma unroll
            for (int j = 0; j < 4; j++) {
                long r = r0 + j;
                if (r < N_ATOMS) {
                    float v = acc[m][n][j] + b;
                    if (ADDX) v += bf2f(Xadd[r * 128 + col]);
                    Out[r * 128 + col] = f2bf(v);
                }
            }
        }
    }
}

// ---------------- readout: per-mol max over 20 atoms (w/ relu) then dot ffn_w ----------
__global__ __launch_bounds__(256) void readout(const u16* __restrict__ ah,
                                               const float* __restrict__ ffn_w,
                                               const float* __restrict__ ffn_b,
                                               float* __restrict__ out) {
    int mol  = blockIdx.x * 4 + (threadIdx.x >> 6);
    int lane = threadIdx.x & 63;
    if (mol >= N_MOLS) return;
    float m0 = -1e30f, m1 = -1e30f;
    const u16* base = ah + (long)mol * APM * 128 + 2 * lane;
#pragma unroll
    for (int a = 0; a < APM; a++) {
        u32 v = *(const u32*)(base + a * 128);
        m0 = fmaxf(m0, bf2f((u16)(v & 0xFFFFu)));
        m1 = fmaxf(m1, bf2f((u16)(v >> 16)));
    }
    m0 = fmaxf(m0, 0.f);  // relu commutes with max
    m1 = fmaxf(m1, 0.f);
    float p = m0 * ffn_w[2 * lane] + m1 * ffn_w[2 * lane + 1];
#pragma unroll
    for (int off = 32; off > 0; off >>= 1) p += __shfl_down(p, off);
    if (lane == 0) out[mol] = p + ffn_b[0];
}

extern "C" void kernel_launch(void* const* d_in, const int* in_sizes, int n_in,
                              void* d_out, int out_size, void* d_ws, size_t ws_size,
                              hipStream_t stream) {
    const float* f_atoms = (const float*)d_in[0];
    const float* f_bonds = (const float*)d_in[1];
    const float* Wi_w = (const float*)d_in[2];
    const float* Wi_b = (const float*)d_in[3];
    const float* Wh_w = (const float*)d_in[4];
    const float* Wh_b = (const float*)d_in[5];
    const float* Wo_w = (const float*)d_in[6];
    const float* Wo_b = (const float*)d_in[7];
    const float* ffn_w = (const float*)d_in[8];
    const float* ffn_b = (const float*)d_in[9];
    const int* a2a = (const int*)d_in[10];
    const int* a2b = (const int*)d_in[11];
    float* out = (float*)d_out;

    char* ws = (char*)d_ws;
    u16* fa    = (u16*)(ws);                  // 500000*160*2 = 160,000,000
    u16* xb    = (u16*)(ws + 160000000L);     // 128,000,000  (pre-relu x, bf16)
    u16* msg   = (u16*)(ws + 288000000L);     // 128,000,000  (pre-relu message / atom_hiddens)
    u16* nsum  = (u16*)(ws + 416000000L);     // 128,000,000  (gathered relu-sum)
    u16* nbond = (u16*)(ws + 544000000L);     // 32,000,000   (bond sums, padded to 32)
    u16* Wip   = (u16*)(ws + 576000000L);     // 40960
    u16* Whp   = (u16*)(ws + 576040960L);     // 40960
    u16* Wop   = (u16*)(ws + 576081920L);     // 73728

    prep_weights<<<64, 256, 0, stream>>>(Wi_w, Wh_w, Wo_w, Wip, Whp, Wop);
    fa_convert<<<39063, 256, 0, stream>>>(f_atoms, fa);
    bond_gather<<<31250, 256, 0, stream>>>(f_bonds, a2b, nbond);

    // x = f_atoms @ Wi^T + b  (pre-relu)
    gemm_mp<5, 0, false><<<3907, 256, 0, stream>>>(fa, 160, (const u16*)nullptr, 0, Wip, Wi_b, (const u16*)nullptr, xb);

    // depth 1
    gather_relu_sum<<<31250, 256, 0, stream>>>(xb, a2a, nsum);
    gemm_mp<4, 1, true><<<3907, 256, 0, stream>>>(nsum, 128, nbond, 32, Whp, Wh_b, xb, msg);
    // depth 2
    gather_relu_sum<<<31250, 256, 0, stream>>>(msg, a2a, nsum);
    gemm_mp<4, 1, true><<<3907, 256, 0, stream>>>(nsum, 128, nbond, 32, Whp, Wh_b, xb, msg);
    // final aggregation + Wo (atom_hiddens pre-relu into msg buffer)
    gather_relu_sum<<<31250, 256, 0, stream>>>(msg, a2a, nsum);
    gemm_mp<5, 4, false><<<3907, 256, 0, stream>>>(fa, 160, nsum, 128, Wop, Wo_b, (const u16*)nullptr, msg);

    readout<<<6250, 256, 0, stream>>>(msg, ffn_w, ffn_b, out);
}

// Round 2
// 1012.474 us; speedup vs baseline: 1.3684x; 1.3684x over previous
//
#include <hip/hip_runtime.h>
#include <hip/hip_bf16.h>

#define N_ATOMS   500000
#define N_BONDS   1000000
#define MAX_NB    6
#define ATOM_FDIM 133
#define BOND_FDIM 14
#define HIDDEN    128
#define N_MOLS    25000
#define APM       20

typedef __attribute__((ext_vector_type(8))) short short8;
typedef __attribute__((ext_vector_type(4))) float f32x4;
typedef unsigned short u16;
typedef unsigned int   u32;

__device__ __forceinline__ float bf2f(u16 u) {
    u32 t = ((u32)u) << 16;
    return __builtin_bit_cast(float, t);
}
__device__ __forceinline__ u16 f2bf(float f) {
    u32 t = __builtin_bit_cast(u32, f);
    t += 0x7FFFu + ((t >> 16) & 1u);
    return (u16)(t >> 16);
}

// ---------------- weight prep: fp32 -> padded bf16 ----------------
__global__ void prep_weights(const float* __restrict__ Wi, const float* __restrict__ Wh,
                             const float* __restrict__ Wo,
                             u16* __restrict__ Wip, u16* __restrict__ Whp, u16* __restrict__ Wop) {
    int stride = gridDim.x * blockDim.x;
    int tid = blockIdx.x * blockDim.x + threadIdx.x;
    for (int i = tid; i < 128 * 160; i += stride) {
        int r = i / 160, c = i % 160;
        Wip[i] = (c < 133) ? f2bf(Wi[r * 133 + c]) : (u16)0;
        Whp[i] = (c < 142) ? f2bf(Wh[r * 142 + c]) : (u16)0;
    }
    for (int i = tid; i < 128 * 288; i += stride) {
        int r = i / 288, c = i % 288;
        float v = 0.f;
        if (c < 133)      v = Wo[r * 261 + c];
        else if (c >= 160) v = Wo[r * 261 + (c - 27)];
        Wop[i] = f2bf(v);
    }
}

// ---------------- f_atoms fp32 [N][133] -> bf16 [N][160] ----------------
__global__ __launch_bounds__(256) void fa_convert(const float* __restrict__ fa, u16* __restrict__ out) {
    long t = (long)blockIdx.x * 256 + threadIdx.x;
    if (t >= (long)N_ATOMS * 20) return;
    int row = (int)(t / 20);
    int c8  = (int)(t % 20) * 8;
    const float* src = fa + (long)row * ATOM_FDIM;
    u16 u[8];
#pragma unroll
    for (int e = 0; e < 8; e++) {
        int c = c8 + e;
        u[e] = (c < ATOM_FDIM) ? f2bf(src[c]) : (u16)0;
    }
    uint4 v;
    v.x = (u32)u[0] | ((u32)u[1] << 16);
    v.y = (u32)u[2] | ((u32)u[3] << 16);
    v.z = (u32)u[4] | ((u32)u[5] << 16);
    v.w = (u32)u[6] | ((u32)u[7] << 16);
    *(uint4*)(out + (long)row * 160 + c8) = v;
}

// ---------------- bond pre-sum: sum_j f_bonds[a2b[:,j]] -> bf16 [N][32] ----------------
__global__ __launch_bounds__(256) void bond_gather(const float* __restrict__ fb, const int* __restrict__ a2b,
                                                   u16* __restrict__ outp) {
    long t = (long)blockIdx.x * 256 + threadIdx.x;
    int atom = (int)(t >> 4);
    int c2   = (int)(t & 15);
    if (atom >= N_ATOMS) return;
    int c0 = 2 * c2, c1 = c0 + 1;
    float s0 = 0.f, s1 = 0.f;
    if (c0 < BOND_FDIM) {
#pragma unroll
        for (int j = 0; j < MAX_NB; j++) {
            int idx = a2b[atom * 6 + j];
            const float* row = fb + (long)idx * BOND_FDIM;
            s0 += row[c0];
            if (c1 < BOND_FDIM) s1 += row[c1];
        }
    }
    *(u32*)(outp + (long)atom * 32 + c0) = (u32)f2bf(s0) | ((u32)f2bf(s1) << 16);
}

// ---------------- gather-relu-sum: dst[a] = sum_j relu(src[a2a[a,j]]) (bf16 128-wide) ---
__global__ __launch_bounds__(256) void gather_relu_sum(const u16* __restrict__ src,
                                                       const int* __restrict__ a2a,
                                                       u16* __restrict__ dst) {
    long t = (long)blockIdx.x * 256 + threadIdx.x;
    int atom = (int)(t >> 4);
    int c8   = (int)(t & 15) << 3;
    float s[8] = {0, 0, 0, 0, 0, 0, 0, 0};
#pragma unroll
    for (int j = 0; j < MAX_NB; j++) {
        int idx = a2a[atom * 6 + j];
        uint4 v = *(const uint4*)(src + (long)idx * 128 + c8);
        u32 w[4] = {v.x, v.y, v.z, v.w};
#pragma unroll
        for (int q = 0; q < 4; q++) {
            s[2 * q]     += fmaxf(bf2f((u16)(w[q] & 0xFFFFu)), 0.f);
            s[2 * q + 1] += fmaxf(bf2f((u16)(w[q] >> 16)), 0.f);
        }
    }
    uint4 o;
    o.x = (u32)f2bf(s[0]) | ((u32)f2bf(s[1]) << 16);
    o.y = (u32)f2bf(s[2]) | ((u32)f2bf(s[3]) << 16);
    o.z = (u32)f2bf(s[4]) | ((u32)f2bf(s[5]) << 16);
    o.w = (u32)f2bf(s[6]) | ((u32)f2bf(s[7]) << 16);
    *(uint4*)(dst + (long)atom * 128 + c8) = o;
}

// ---------------- GEMM: Out[N][128] = concat(A0,A1)[N][32*KB] @ Wp^T + bias (+Xadd) ----
// Swapped-operand MFMA: mfma(Wfrag, xfrag, acc) -> D[ocol][atom]; lane holds
// atom = tile*16 + (lane&15), ocols = (lane>>4)*4 + {0..3}  => 8B packed stores.
template <int KB0, int KB1, bool ADDX>
__global__ __launch_bounds__(512, 4) void gemm_mp(const u16* __restrict__ A0, int ldA0,
                                                  const u16* __restrict__ A1, int ldA1,
                                                  const u16* __restrict__ Wp,
                                                  const float* __restrict__ bias,
                                                  const u16* __restrict__ Xadd,
                                                  u16* __restrict__ Out) {
    constexpr int KB  = KB0 + KB1;
    constexpr int KP  = KB * 32;
    constexpr int LDW = KP + 8;  // +8 bf16 pad: 2-way LDS bank alias only
    __shared__ u16 ldsw[128 * LDW];
    for (int i = threadIdx.x; i < 128 * (KP / 8); i += 512) {
        int r  = i / (KP / 8);
        int c8 = (i % (KP / 8)) * 8;
        *(uint4*)(&ldsw[r * LDW + c8]) = *(const uint4*)(Wp + r * KP + c8);
    }
    __syncthreads();

    const int lane = threadIdx.x & 63;
    const int wave = threadIdx.x >> 6;
    const int lrow = lane & 15;   // atom within 16-tile / W row within 16-tile
    const int kg   = lane >> 4;   // k-group 0..3
    const long rowbase = (long)blockIdx.x * 256 + wave * 32;

    f32x4 acc[2][8];
#pragma unroll
    for (int m = 0; m < 2; m++)
#pragma unroll
        for (int n = 0; n < 8; n++) acc[m][n] = (f32x4){0.f, 0.f, 0.f, 0.f};

    long ar[2];
#pragma unroll
    for (int m = 0; m < 2; m++) {
        long r = rowbase + m * 16 + lrow;
        if (r >= N_ATOMS) r = N_ATOMS - 1;  // clamp (stores are guarded)
        ar[m] = r;
    }

#pragma unroll
    for (int kb = 0; kb < KB; kb++) {
        const u16* As;
        int ld, koff;
        if (kb < KB0) { As = A0; ld = ldA0; koff = kb * 32; }
        else          { As = A1; ld = ldA1; koff = (kb - KB0) * 32; }
        short8 af[2];
#pragma unroll
        for (int m = 0; m < 2; m++)
            af[m] = __builtin_bit_cast(short8, *(const uint4*)(As + ar[m] * ld + koff + kg * 8));
#pragma unroll
        for (int n = 0; n < 8; n++) {
            short8 bf = __builtin_bit_cast(short8, *(const uint4*)(&ldsw[(n * 16 + lrow) * LDW + kb * 32 + kg * 8]));
            // swapped operands: A = weight frag, B = x frag -> D[ocol][atom]
            acc[0][n] = __builtin_amdgcn_mfma_f32_16x16x32_bf16(bf, af[0], acc[0][n], 0, 0, 0);
            acc[1][n] = __builtin_amdgcn_mfma_f32_16x16x32_bf16(bf, af[1], acc[1][n], 0, 0, 0);
        }
    }

#pragma unroll
    for (int m = 0; m < 2; m++) {
        long r = rowbase + m * 16 + lrow;
        if (r >= N_ATOMS) continue;
#pragma unroll
        for (int n = 0; n < 8; n++) {
            int c0 = n * 16 + kg * 4;
            float4 b4 = *(const float4*)(bias + c0);
            float v0 = acc[m][n][0] + b4.x;
            float v1 = acc[m][n][1] + b4.y;
            float v2 = acc[m][n][2] + b4.z;
            float v3 = acc[m][n][3] + b4.w;
            if (ADDX) {
                uint2 xv = *(const uint2*)(Xadd + r * 128 + c0);
                v0 += bf2f((u16)(xv.x & 0xFFFFu));
                v1 += bf2f((u16)(xv.x >> 16));
                v2 += bf2f((u16)(xv.y & 0xFFFFu));
                v3 += bf2f((u16)(xv.y >> 16));
            }
            uint2 o;
            o.x = (u32)f2bf(v0) | ((u32)f2bf(v1) << 16);
            o.y = (u32)f2bf(v2) | ((u32)f2bf(v3) << 16);
            *(uint2*)(Out + r * 128 + c0) = o;
        }
    }
}

// ---------------- readout: per-mol max over 20 atoms (w/ relu) then dot ffn_w ----------
__global__ __launch_bounds__(256) void readout(const u16* __restrict__ ah,
                                               const float* __restrict__ ffn_w,
                                               const float* __restrict__ ffn_b,
                                               float* __restrict__ out) {
    int mol  = blockIdx.x * 4 + (threadIdx.x >> 6);
    int lane = threadIdx.x & 63;
    if (mol >= N_MOLS) return;
    float m0 = -1e30f, m1 = -1e30f;
    const u16* base = ah + (long)mol * APM * 128 + 2 * lane;
#pragma unroll
    for (int a = 0; a < APM; a++) {
        u32 v = *(const u32*)(base + a * 128);
        m0 = fmaxf(m0, bf2f((u16)(v & 0xFFFFu)));
        m1 = fmaxf(m1, bf2f((u16)(v >> 16)));
    }
    m0 = fmaxf(m0, 0.f);  // relu commutes with max
    m1 = fmaxf(m1, 0.f);
    float p = m0 * ffn_w[2 * lane] + m1 * ffn_w[2 * lane + 1];
#pragma unroll
    for (int off = 32; off > 0; off >>= 1) p += __shfl_down(p, off);
    if (lane == 0) out[mol] = p + ffn_b[0];
}

extern "C" void kernel_launch(void* const* d_in, const int* in_sizes, int n_in,
                              void* d_out, int out_size, void* d_ws, size_t ws_size,
                              hipStream_t stream) {
    const float* f_atoms = (const float*)d_in[0];
    const float* f_bonds = (const float*)d_in[1];
    const float* Wi_w = (const float*)d_in[2];
    const float* Wi_b = (const float*)d_in[3];
    const float* Wh_w = (const float*)d_in[4];
    const float* Wh_b = (const float*)d_in[5];
    const float* Wo_w = (const float*)d_in[6];
    const float* Wo_b = (const float*)d_in[7];
    const float* ffn_w = (const float*)d_in[8];
    const float* ffn_b = (const float*)d_in[9];
    const int* a2a = (const int*)d_in[10];
    const int* a2b = (const int*)d_in[11];
    float* out = (float*)d_out;

    char* ws = (char*)d_ws;
    u16* fa    = (u16*)(ws);                  // 160,000,000
    u16* xb    = (u16*)(ws + 160000000L);     // 128,000,000  (pre-relu x)
    u16* msg   = (u16*)(ws + 288000000L);     // 128,000,000  (pre-relu message / atom_hiddens)
    u16* nsum  = (u16*)(ws + 416000000L);     // 128,000,000  (gathered relu-sum)
    u16* nbond = (u16*)(ws + 544000000L);     // 32,000,000   (bond sums, padded to 32)
    u16* Wip   = (u16*)(ws + 576000000L);     // 40960
    u16* Whp   = (u16*)(ws + 576040960L);     // 40960
    u16* Wop   = (u16*)(ws + 576081920L);     // 73728

    prep_weights<<<64, 256, 0, stream>>>(Wi_w, Wh_w, Wo_w, Wip, Whp, Wop);
    fa_convert<<<39063, 256, 0, stream>>>(f_atoms, fa);
    bond_gather<<<31250, 256, 0, stream>>>(f_bonds, a2b, nbond);

    // x = f_atoms @ Wi^T + b  (pre-relu)
    gemm_mp<5, 0, false><<<1954, 512, 0, stream>>>(fa, 160, (const u16*)nullptr, 0, Wip, Wi_b, (const u16*)nullptr, xb);

    // depth 1
    gather_relu_sum<<<31250, 256, 0, stream>>>(xb, a2a, nsum);
    gemm_mp<4, 1, true><<<1954, 512, 0, stream>>>(nsum, 128, nbond, 32, Whp, Wh_b, xb, msg);
    // depth 2
    gather_relu_sum<<<31250, 256, 0, stream>>>(msg, a2a, nsum);
    gemm_mp<4, 1, true><<<1954, 512, 0, stream>>>(nsum, 128, nbond, 32, Whp, Wh_b, xb, msg);
    // final aggregation + Wo (atom_hiddens pre-relu into msg buffer)
    gather_relu_sum<<<31250, 256, 0, stream>>>(msg, a2a, nsum);
    gemm_mp<5, 4, false><<<1954, 512, 0, stream>>>(fa, 160, nsum, 128, Wop, Wo_b, (const u16*)nullptr, msg);

    readout<<<6250, 256, 0, stream>>>(msg, ffn_w, ffn_b, out);
}